// Round 18
// baseline (188.375 us; speedup 1.0000x reference)
//
// Swin block fwd, MI355X gfx950. Round 18: k_attn Q/K fully in registers — swapped-operand QKV
// (mfma16(W,X) -> D[channel][token]) feeds mfma16x16 scores directly (validated D-row = A/B-frag
// k-layout identity). Kills 64 ds_write_b16 + 8 ds_read_b128 per thread. V/softmax/PV unchanged.
// k_mlp2 (R17 triple-buffer, 117us) and k_prep unchanged.
#include <hip/hip_runtime.h>
#include <math.h>

typedef __attribute__((ext_vector_type(8))) short bf16x8;
typedef __attribute__((ext_vector_type(4))) short bf16x4;
typedef __attribute__((ext_vector_type(4))) float f32x4;
typedef __attribute__((ext_vector_type(4))) unsigned short u16x4;

#define DEVI __device__ __forceinline__

DEVI float b2f(unsigned int u){ union{unsigned int i; float f;} c; c.i = u<<16; return c.f; }
DEVI unsigned short f2b(float f){
  union{float f; unsigned int i;} c; c.f = f;
  unsigned int r = c.i + 0x7fffu + ((c.i>>16)&1u);
  return (unsigned short)(r>>16);
}
DEVI unsigned int pack2(float a, float b){
  return (unsigned int)f2b(a) | ((unsigned int)f2b(b)<<16);
}
DEVI void unpack8(uint4 u, float* f){
  f[0]=b2f(u.x&0xffffu); f[1]=b2f(u.x>>16);
  f[2]=b2f(u.y&0xffffu); f[3]=b2f(u.y>>16);
  f[4]=b2f(u.z&0xffffu); f[5]=b2f(u.z>>16);
  f[6]=b2f(u.w&0xffffu); f[7]=b2f(u.w>>16);
}
DEVI f32x4 mfma16(bf16x8 a, bf16x8 b, f32x4 c){
  return __builtin_amdgcn_mfma_f32_16x16x32_bf16(a, b, c, 0, 0, 0);
}
DEVI f32x4 mfma16x16(bf16x4 a, bf16x4 b, f32x4 c){
#if __has_builtin(__builtin_amdgcn_mfma_f32_16x16x16bf16_1k)
  return __builtin_amdgcn_mfma_f32_16x16x16bf16_1k(a, b, c, 0, 0, 0);
#else
  f32x4 d = c;
  asm volatile("v_mfma_f32_16x16x16_bf16 %0, %1, %2, %0" : "+v"(d) : "v"(a), "v"(b));
  return d;
#endif
}
// gelu tanh-form as u * sigmoid(2y)
DEVI float gelu_fast(float u){
  const float y2 = 1.5957691216057308f*(u + 0.044715f*u*u*u);
  return u / (1.f + __expf(-y2));
}
// XOR swizzles
DEVI int swzA(int row, int byi){ return row*256 + (byi ^ ((row&7)<<4)); }      // rows x 128 bf16
DEVI int swzO(int row, int byc){ return row*512 + (byc ^ ((row&7)<<4) ^ (((byc>>7)&3)<<5)); } // 64x128 f32

// ---------------- K0: weights -> bf16 MFMA-fragment order + rpb expansion ----------------
__global__ void k_prep(const float* __restrict__ qkvw, const float* __restrict__ projw,
                       const float* __restrict__ w1,   const float* __restrict__ w2,
                       const float* __restrict__ rpbt,
                       ushort* __restrict__ qkvF, ushort* __restrict__ projF,
                       ushort* __restrict__ w1F,  ushort* __restrict__ w2F,
                       ushort* __restrict__ rpbE)
{
  const int t = blockIdx.x*256 + threadIdx.x;   // 0..16383
  const int l = t&63, fr = t>>6;                // frag id 0..255
  const int l15 = l&15, l4 = l>>4;
  { // rpbE[head][q][k] bf16
    const int head = t>>12, q = (t>>6)&63, k = t&63;
    const int di = (q>>3)-(k>>3)+7, dj = (q&7)-(k&7)+7;
    rpbE[t] = f2b(rpbt[(di*15+dj)*4 + head]);
  }
  { // w2F: 256 frags x 512B ; lane: w2[hid0+e][oc], e=0..3
    const int c = fr>>5, og = (fr>>2)&7, h = fr&3;
    const int oc = og*16 + l15, hid0 = c*64 + h*16 + l4*4;
    ushort* d = w2F + (size_t)fr*256 + l*4;
    #pragma unroll
    for(int e=0;e<4;e++) d[e] = f2b(w2[(size_t)(hid0+e)*128 + oc]);
  }
  if (fr < 128){ // w1F
    const int c = fr>>4, hg = (fr>>2)&3, kk = fr&3;
    const int hid = c*64 + hg*16 + l15, k0 = kk*32 + l4*8;
    ushort* d = w1F + (size_t)fr*512 + l*8;
    #pragma unroll
    for(int e=0;e<8;e++) d[e] = f2b(w1[(size_t)(k0+e)*512 + hid]);
  }
  if (fr < 96){ // qkvF: fr = (s3*8+g)*4+kk
    const int s3 = fr>>5, g = (fr>>2)&7, kk = fr&3;
    const int col = s3*128 + g*16 + l15, k0 = kk*32 + l4*8;
    ushort* d = qkvF + (size_t)fr*512 + l*8;
    #pragma unroll
    for(int e=0;e<8;e++) d[e] = f2b(qkvw[(size_t)(k0+e)*384 + col]);
  }
  if (fr < 32){ // projF
    const int g = fr>>2, kk = fr&3;
    const int col = g*16 + l15, k0 = kk*32 + l4*8;
    ushort* d = projF + (size_t)fr*512 + l*8;
    #pragma unroll
    for(int e=0;e<8;e++) d[e] = f2b(projw[(size_t)(k0+e)*128 + col]);
  }
}

// ---------------- K1: fused window attention (Q/K in registers) ----------------
__global__ __launch_bounds__(256,3) void k_attn(
    const float*  __restrict__ x,
    const float*  __restrict__ g1, const float* __restrict__ be1,
    const ushort* __restrict__ qkvF, const float* __restrict__ qkvb,
    const ushort* __restrict__ projF, const float* __restrict__ projb,
    const ushort* __restrict__ rpbE,
    ushort* __restrict__ x2w)
{
  __shared__ __align__(16) char smem[49152];
  const int tid  = threadIdx.x;
  const int wave = tid>>6, lane = tid&63;
  const int l15 = lane&15, l4 = lane>>4;
  const int wid = blockIdx.x;
  const int b   = wid>>6, wim = wid&63;
  const int wh  = wim>>3, wv = wim&7;

  char* const smA  = smem;                      // 16 KB: LN1 tile / attn-O
  char* const smR  = smem + 16384;              // 32 KB fp32 proj restage

  const f32x4 Z = {0.f,0.f,0.f,0.f};
  const int t_row = tid>>2;
  const int cg    = (tid&3)*32;
  const int ti_r = t_row>>3, tj_r = t_row&7;
  const int ho_r = (wh*8+ti_r+4)&63, wo_r = (wv*8+tj_r+4)&63;
  const size_t growbase = ((size_t)(b*4096 + ho_r*64 + wo_r))*128;

  float xraw[32];   // shifted-gathered x row-chunk: kept live for the residual

  { // ---- Phase 1: gather (roll -4,-4) + LN1 -> smA ----
    const float* src = x + growbase + cg;
    #pragma unroll
    for(int q=0;q<8;q++){
      const float4 f4 = *(const float4*)(src + q*4);
      xraw[q*4+0]=f4.x; xraw[q*4+1]=f4.y; xraw[q*4+2]=f4.z; xraw[q*4+3]=f4.w;
    }
    float s=0.f, ss=0.f;
    #pragma unroll
    for(int e=0;e<32;e++){ s+=xraw[e]; ss+=xraw[e]*xraw[e]; }
    s += __shfl_xor(s,1); ss += __shfl_xor(ss,1);
    s += __shfl_xor(s,2); ss += __shfl_xor(ss,2);
    const float mean = s*(1.f/128.f);
    const float varv = fmaxf(ss*(1.f/128.f) - mean*mean, 0.f);
    const float rstd = rsqrtf(varv + 1e-5f);
    #pragma unroll
    for(int q=0;q<4;q++){
      const float4 ga = *(const float4*)(g1 +cg+q*8);
      const float4 gb = *(const float4*)(g1 +cg+q*8+4);
      const float4 ba = *(const float4*)(be1+cg+q*8);
      const float4 bb = *(const float4*)(be1+cg+q*8+4);
      const float* vp = xraw + q*8;
      uint4 pk;
      pk.x = pack2((vp[0]-mean)*rstd*ga.x+ba.x, (vp[1]-mean)*rstd*ga.y+ba.y);
      pk.y = pack2((vp[2]-mean)*rstd*ga.z+ba.z, (vp[3]-mean)*rstd*ga.w+ba.w);
      pk.z = pack2((vp[4]-mean)*rstd*gb.x+bb.x, (vp[5]-mean)*rstd*gb.y+bb.y);
      pk.w = pack2((vp[6]-mean)*rstd*gb.z+bb.z, (vp[7]-mean)*rstd*gb.w+bb.w);
      *(uint4*)(smA + swzA(t_row, cg*2 + q*16)) = pk;
    }
  }
  __syncthreads();

  const int headc = wave*32;
  bf16x4 Qr[4][2], Kr[4][2], Vf[4][2];

  { // ---- Phase 2: QKV. Q,K swapped (D[channel][token]) -> regs; V normal -> regs ----
    #pragma unroll
    for(int s3=0;s3<2;s3++){        // Q then K: swapped operands
      f32x4 acc[4][2];
      #pragma unroll
      for(int tg=0;tg<4;tg++){ acc[tg][0]=Z; acc[tg][1]=Z; }
      bf16x8 wfr[2][4];
      #pragma unroll
      for(int ct=0;ct<2;ct++)
        #pragma unroll
        for(int kk=0;kk<4;kk++)
          wfr[ct][kk] = *(const bf16x8*)(qkvF + (size_t)((s3*8 + wave*2 + ct)*4 + kk)*512 + lane*8);
      #pragma unroll
      for(int kk=0;kk<4;kk++){
        bf16x8 xfr[4];
        #pragma unroll
        for(int tg=0;tg<4;tg++)
          xfr[tg] = *(const bf16x8*)(smA + swzA(tg*16+l15, kk*64 + l4*16));
        #pragma unroll
        for(int tg=0;tg<4;tg++)
          #pragma unroll
          for(int ct=0;ct<2;ct++)
            acc[tg][ct] = mfma16(wfr[ct][kk], xfr[tg], acc[tg][ct]);   // D: col=token, row=channel
      }
      const float sc = (s3==0) ? 0.17677669529663687f : 1.f;
      #pragma unroll
      for(int ct=0;ct<2;ct++){
        const float4 b4 = *(const float4*)(qkvb + s3*128 + headc + ct*16 + l4*4);
        #pragma unroll
        for(int tg=0;tg<4;tg++){
          union { uint2 u; bf16x4 v; } cv;
          cv.u.x = pack2((acc[tg][ct][0]+b4.x)*sc, (acc[tg][ct][1]+b4.y)*sc);
          cv.u.y = pack2((acc[tg][ct][2]+b4.z)*sc, (acc[tg][ct][3]+b4.w)*sc);
          if (s3==0) Qr[tg][ct] = cv.v; else Kr[tg][ct] = cv.v;
        }
      }
    }
    { // V: normal orientation (D[token][channel]) for PV B-frags
      f32x4 acc[4][2];
      #pragma unroll
      for(int rt=0;rt<4;rt++){ acc[rt][0]=Z; acc[rt][1]=Z; }
      bf16x8 bfr[2][4];
      #pragma unroll
      for(int ct=0;ct<2;ct++)
        #pragma unroll
        for(int kk=0;kk<4;kk++)
          bfr[ct][kk] = *(const bf16x8*)(qkvF + (size_t)((16 + wave*2 + ct)*4 + kk)*512 + lane*8);
      #pragma unroll
      for(int kk=0;kk<4;kk++){
        bf16x8 afr[4];
        #pragma unroll
        for(int rt=0;rt<4;rt++)
          afr[rt] = *(const bf16x8*)(smA + swzA(rt*16+l15, kk*64 + l4*16));
        #pragma unroll
        for(int rt=0;rt<4;rt++)
          #pragma unroll
          for(int ct=0;ct<2;ct++)
            acc[rt][ct] = mfma16(afr[rt], bfr[ct][kk], acc[rt][ct]);
      }
      #pragma unroll
      for(int ct=0;ct<2;ct++){
        const float bias = qkvb[256 + headc + ct*16 + l15];
        #pragma unroll
        for(int rt=0;rt<4;rt++){
          union { uint2 u; bf16x4 v; } cv;
          cv.u.x = pack2(acc[rt][ct][0]+bias, acc[rt][ct][1]+bias);
          cv.u.y = pack2(acc[rt][ct][2]+bias, acc[rt][ct][3]+bias);
          Vf[rt][ct] = cv.v;
        }
      }
    }
  }
  __syncthreads();  // all waves done reading smA (it becomes O below)

  // ---- Phase 3+4: scores (mfma16x16 from regs) + rpb + mask + softmax + PV ----
  f32x4 O[4][2];
  #pragma unroll
  for(int rt=0;rt<4;rt++){ O[rt][0]=Z; O[rt][1]=Z; }
  {
    const bool edge = (wh==7) || (wv==7);
    #pragma unroll
    for(int rt=0; rt<4; ++rt){
      f32x4 S[4];
      #pragma unroll
      for(int g=0; g<4; ++g)
        S[g] = mfma16x16(Kr[g][0], Qr[rt][0], Z);      // S: col=q(l15), row=ktok(l4*4+j)
      #pragma unroll
      for(int g=0; g<4; ++g)
        S[g] = mfma16x16(Kr[g][1], Qr[rt][1], S[g]);
      const int q = rt*16 + l15;
      int regq = 0;
      if (edge){
        const int qi=q>>3, qj=q&7;
        regq = ((wh<7)?0:((qi<4)?1:2))*3 + ((wv<7)?0:((qj<4)?1:2));
      }
      const ushort* rbase = rpbE + wave*4096 + q*64 + l4*4;
      #pragma unroll
      for(int g=0; g<4; ++g){
        const u16x4 rb = *(const u16x4*)(rbase + g*16);
        #pragma unroll
        for(int j=0;j<4;j++){
          float add = b2f(rb[j]);
          if (edge){
            const int k = g*16 + l4*4 + j;
            const int ki=k>>3, kj=k&7;
            const int regk = ((wh<7)?0:((ki<4)?1:2))*3 + ((wv<7)?0:((kj<4)?1:2));
            if (regk != regq) add -= 100.f;
          }
          S[g][j] += add;
        }
      }
      float mx = -1e30f;
      #pragma unroll
      for(int g=0;g<4;g++)
        #pragma unroll
        for(int j=0;j<4;j++) mx = fmaxf(mx, S[g][j]);
      mx = fmaxf(mx, __shfl_xor(mx,16));
      mx = fmaxf(mx, __shfl_xor(mx,32));
      float sm = 0.f;
      #pragma unroll
      for(int g=0;g<4;g++)
        #pragma unroll
        for(int j=0;j<4;j++){ const float e = __expf(S[g][j]-mx); S[g][j]=e; sm+=e; }
      sm += __shfl_xor(sm,16);
      sm += __shfl_xor(sm,32);
      const float inv = 1.f/sm;
      #pragma unroll
      for(int g=0;g<4;g++){
        union { uint2 u; bf16x4 v; } cv;
        cv.u.x = pack2(S[g][0]*inv, S[g][1]*inv);
        cv.u.y = pack2(S[g][2]*inv, S[g][3]*inv);
        #pragma unroll
        for(int cvi=0;cvi<2;cvi++)
          O[rt][cvi] = mfma16x16(cv.v, Vf[g][cvi], O[rt][cvi]);
      }
    }
    #pragma unroll
    for(int rt=0;rt<4;rt++)
      #pragma unroll
      for(int cvi=0;cvi<2;cvi++)
        #pragma unroll
        for(int j=0;j<4;j++)
          *(ushort*)(smA + swzA(rt*16+l4*4+j, (headc + cvi*16 + l15)*2)) = f2b(O[rt][cvi][j]);
  }
  __syncthreads();

  { // ---- Phase 5: proj + bias -> smR (fp32, swzO) ----
    f32x4 PR[4][2];
    #pragma unroll
    for(int rt=0;rt<4;rt++){ PR[rt][0]=Z; PR[rt][1]=Z; }
    bf16x8 pb[2][4];
    #pragma unroll
    for(int ct=0;ct<2;ct++)
      #pragma unroll
      for(int kk=0;kk<4;kk++)
        pb[ct][kk] = *(const bf16x8*)(projF + (size_t)((wave*2+ct)*4 + kk)*512 + lane*8);
    #pragma unroll
    for(int kk=0;kk<4;kk++){
      bf16x8 afr[4];
      #pragma unroll
      for(int rt=0;rt<4;rt++)
        afr[rt] = *(const bf16x8*)(smA + swzA(rt*16+l15, kk*64 + l4*16));
      #pragma unroll
      for(int rt=0;rt<4;rt++)
        #pragma unroll
        for(int ct=0;ct<2;ct++)
          PR[rt][ct] = mfma16(afr[rt], pb[ct][kk], PR[rt][ct]);
    }
    #pragma unroll
    for(int ct=0;ct<2;ct++){
      const int col = headc + ct*16 + l15;
      const float bias = projb[col];
      #pragma unroll
      for(int rt=0;rt<4;rt++)
        #pragma unroll
        for(int j=0;j<4;j++)
          *(float*)(smR + swzO(rt*16+l4*4+j, col*4)) = PR[rt][ct][j] + bias;
    }
  }
  __syncthreads();

  { // ---- Phase 6: x2 = x(regs) + projout; uint4 stores ----
    ushort* drow = x2w + ((size_t)(wid*64 + t_row))*128 + cg;
    #pragma unroll
    for(int q=0;q<4;q++){
      const f32x4 oa = *(const f32x4*)(smR + swzO(t_row, (cg+q*8  )*4));
      const f32x4 ob = *(const f32x4*)(smR + swzO(t_row, (cg+q*8+4)*4));
      const float* vp = xraw + q*8;
      uint4 pk;
      pk.x = pack2(oa[0]+vp[0], oa[1]+vp[1]);
      pk.y = pack2(oa[2]+vp[2], oa[3]+vp[3]);
      pk.z = pack2(ob[0]+vp[4], ob[1]+vp[5]);
      pk.w = pack2(ob[2]+vp[6], ob[3]+vp[7]);
      *(uint4*)(drow + q*8) = pk;
    }
  }
}

// ---------------- K2: MLP, triple-buffered weights, ONE barrier per chunk (R17) ----------------
__global__ __launch_bounds__(1024) void k_mlp2(
    const ushort* __restrict__ x2w,
    const float* __restrict__ g2, const float* __restrict__ be2,
    const ushort* __restrict__ w1F, const float* __restrict__ bb1,
    const ushort* __restrict__ w2F, const float* __restrict__ bb2,
    float* __restrict__ outp)
{
  extern __shared__ __align__(16) char smem[];  // 100352 B: buf0/1/2 at 0/32K/64K (+smB1 at 96K)
  float* const smB1 = (float*)(smem + 98304);
  const int tid  = threadIdx.x;
  const int wave = tid>>6, lane = tid&63;      // wave 0..15
  const int l15 = lane&15, l4 = lane>>4;
  const int gblk = blockIdx.x;                 // 0..511 (4 windows each)
  const f32x4 Z = {0.f,0.f,0.f,0.f};

  if (tid < 512) smB1[tid] = bb1[tid];

  // ---- LN2: single pass, 256 tokens -> smem[0,64K) (swzA) ----
  {
    const int tk = tid>>2;
    const int cg = (tid&3)*32;
    const ushort* src = x2w + ((size_t)(gblk*256 + tk))*128 + cg;
    float v[32];
    unpack8(*(const uint4*)(src   ), v   );
    unpack8(*(const uint4*)(src+ 8), v+ 8);
    unpack8(*(const uint4*)(src+16), v+16);
    unpack8(*(const uint4*)(src+24), v+24);
    float s=0.f, ss=0.f;
    #pragma unroll
    for(int e=0;e<32;e++){ s+=v[e]; ss+=v[e]*v[e]; }
    s += __shfl_xor(s,1); ss += __shfl_xor(ss,1);
    s += __shfl_xor(s,2); ss += __shfl_xor(ss,2);
    const float mean = s*(1.f/128.f);
    const float varv = fmaxf(ss*(1.f/128.f) - mean*mean, 0.f);
    const float rstd = rsqrtf(varv + 1e-5f);
    #pragma unroll
    for(int q=0;q<4;q++){
      const float4 ga = *(const float4*)(g2 +cg+q*8);
      const float4 gb = *(const float4*)(g2 +cg+q*8+4);
      const float4 ba = *(const float4*)(be2+cg+q*8);
      const float4 bb = *(const float4*)(be2+cg+q*8+4);
      const float* vp = v + q*8;
      uint4 pk;
      pk.x = pack2((vp[0]-mean)*rstd*ga.x+ba.x, (vp[1]-mean)*rstd*ga.y+ba.y);
      pk.y = pack2((vp[2]-mean)*rstd*ga.z+ba.z, (vp[3]-mean)*rstd*ga.w+ba.w);
      pk.z = pack2((vp[4]-mean)*rstd*gb.x+bb.x, (vp[5]-mean)*rstd*gb.y+bb.y);
      pk.w = pack2((vp[6]-mean)*rstd*gb.z+bb.z, (vp[7]-mean)*rstd*gb.w+bb.w);
      *(uint4*)(smem + swzA(tk, cg*2 + q*16)) = pk;
    }
  }
  __syncthreads();

  // ---- extract X fragments to registers (smX dies after this) ----
  const int trow = wave*16 + l15;   // this wave's 16 tokens
  bf16x8 xf[4];
  #pragma unroll
  for(int kk=0;kk<4;++kk)
    xf[kk] = *(const bf16x8*)(smem + swzA(trow, kk*64 + l4*16));
  __syncthreads();   // all waves done reading smX -> weight buffers may overwrite

  // ---- async weight staging: waves 0-7 stage w1 (16KB), waves 8-15 stage w2 (16KB) ----
  const ushort* const wsrc = (wave<8) ? w1F : w2F;
  const int ldsoff = ((wave<8)?0:16384) + (wave&7)*2048;   // byte offset within buf
  const int subsh  = (wave&7)*1024;                        // ushort offset within 8192-ushort chunk
  #define STAGE_CHUNK(cc, bufbase) do{ \
    const ushort* gsrc = wsrc + (size_t)(cc)*8192 + subsh + lane*8; \
    char* lb = (bufbase) + ldsoff; \
    __builtin_amdgcn_global_load_lds((const unsigned int*)(gsrc     ), (unsigned int*)(lb      ), 16, 0, 0); \
    __builtin_amdgcn_global_load_lds((const unsigned int*)(gsrc+512 ), (unsigned int*)(lb+1024 ), 16, 0, 0); \
  }while(0)

  STAGE_CHUNK(0, smem);
  STAGE_CHUNK(1, smem + 32768);

  f32x4 OA[8];
  #pragma unroll
  for(int ocg=0;ocg<8;++ocg) OA[ocg]=Z;

  for (int c=0; c<8; ++c){
    if (c < 7) asm volatile("s_waitcnt vmcnt(2)" ::: "memory");
    else       asm volatile("s_waitcnt vmcnt(0)" ::: "memory");
    __builtin_amdgcn_s_barrier();          // chunk c landed everywhere; all waves finished iter c-1
    __builtin_amdgcn_sched_barrier(0);
    if (c < 6) STAGE_CHUNK(c+2, smem + 32768*((c+2)%3));

    char* const buf = smem + 32768*(c%3);
    const int hidb = c*64;
    f32x4 acc1[4] = {Z,Z,Z,Z};
    #pragma unroll
    for(int hg=0; hg<4; ++hg)
      #pragma unroll
      for(int kk=0; kk<4; ++kk){
        const bf16x8 wf = *(const bf16x8*)(buf + (hg*4+kk)*1024 + lane*16);
        acc1[hg] = mfma16(wf, xf[kk], acc1[hg]);
      }
    bf16x4 Hf[4];
    #pragma unroll
    for(int hg=0; hg<4; ++hg){
      const float4 b4 = *(const float4*)(&smB1[hidb + hg*16 + l4*4]);
      bf16x4 hv;
      hv[0] = (short)f2b(gelu_fast(acc1[hg][0]+b4.x));
      hv[1] = (short)f2b(gelu_fast(acc1[hg][1]+b4.y));
      hv[2] = (short)f2b(gelu_fast(acc1[hg][2]+b4.z));
      hv[3] = (short)f2b(gelu_fast(acc1[hg][3]+b4.w));
      Hf[hg] = hv;
    }
    #pragma unroll
    for(int ocg=0; ocg<8; ++ocg)
      #pragma unroll
      for(int hg=0; hg<4; ++hg){
        const bf16x4 w2f = *(const bf16x4*)(buf + 16384 + (ocg*4+hg)*512 + lane*8);
        OA[ocg] = mfma16x16(w2f, Hf[hg], OA[ocg]);
      }
    __builtin_amdgcn_sched_barrier(0);
  }
  #undef STAGE_CHUNK

  // ---- epilogue: restage raw x2 into smem[0,64K) (aliases bufs; safe after barrier) ----
  __syncthreads();
  {
    const int tk = tid>>2;
    const int cg = (tid&3)*32;
    const uint4* src = (const uint4*)(x2w + ((size_t)(gblk*256 + tk))*128 + cg);
    #pragma unroll
    for(int q=0;q<4;q++) *(uint4*)(smem + swzA(tk, cg*2 + q*16)) = src[q];
  }
  __syncthreads();
  {
    const int tk  = trow;
    const int wid = gblk*4 + (tk>>6);
    const int n   = tk & 63;
    const int bb  = wid>>6, wim = wid&63;
    const int wh  = wim>>3, wv = wim&7;
    const int ti  = n>>3,  tj = n&7;
    const int ho  = (wh*8+ti+4)&63, wo = (wv*8+tj+4)&63;
    float* const drow = outp + ((size_t)(bb*4096 + ho*64 + wo))*128;
    #pragma unroll
    for(int ocg=0; ocg<8; ++ocg){
      const int oc = ocg*16 + l4*4;
      const float4 b4 = *(const float4*)(bb2 + oc);
      const u16x4 xr = *(const u16x4*)(smem + swzA(tk, oc*2));
      f32x4 r = OA[ocg];
      r[0] += b4.x + b2f(xr[0]);
      r[1] += b4.y + b2f(xr[1]);
      r[2] += b4.z + b2f(xr[2]);
      r[3] += b4.w + b2f(xr[3]);
      *(f32x4*)(drow + oc) = r;   // plain store: L2 write-combines full lines
    }
  }
}

extern "C" void kernel_launch(void* const* d_in, const int* in_sizes, int n_in,
                              void* d_out, int out_size, void* d_ws, size_t ws_size,
                              hipStream_t stream) {
  (void)in_sizes; (void)n_in; (void)out_size; (void)ws_size;
  const float* x     = (const float*)d_in[0];
  const float* n1g   = (const float*)d_in[1];
  const float* n1b   = (const float*)d_in[2];
  const float* qkvw  = (const float*)d_in[3];
  const float* qkvb  = (const float*)d_in[4];
  const float* projw = (const float*)d_in[5];
  const float* projb = (const float*)d_in[6];
  const float* rpbt  = (const float*)d_in[7];
  const float* n2g   = (const float*)d_in[8];
  const float* n2b   = (const float*)d_in[9];
  const float* w1    = (const float*)d_in[10];
  const float* b1    = (const float*)d_in[11];
  const float* w2    = (const float*)d_in[12];
  const float* b2    = (const float*)d_in[13];
  float* outp = (float*)d_out;

  ushort* ws    = (ushort*)d_ws;
  ushort* x2w   = ws;                  // 16,777,216 bf16
  ushort* qkvF  = ws + 16777216;       // 49152
  ushort* projF = qkvF + 49152;        // 16384
  ushort* w1F   = projF + 16384;       // 65536 (8 chunks x 8192)
  ushort* w2F   = w1F + 65536;         // 65536 (8 chunks x 8192)
  ushort* rpbE  = w2F + 65536;         // 16384

  k_prep<<<64, 256, 0, stream>>>(qkvw, projw, w1, w2, rpbt, qkvF, projF, w1F, w2F, rpbE);
  k_attn<<<2048, 256, 0, stream>>>(x, n1g, n1b, qkvF, qkvb, projF, projb, rpbE, x2w);
  k_mlp2<<<512, 1024, 100352, stream>>>(x2w, n2g, n2b, w1F, b1, w2F, b2, outp);
}

// Round 19
// 173.480 us; speedup vs baseline: 1.0859x; 1.0859x over previous
//
// Swin block fwd, MI355X gfx950. Round 19: exact revert to R17 (best validated: 173.2us).
// R18's Q/K-in-regs spilled (WRITE 116MB scratch traffic, k_attn 52->124us) — reverted.
// K1: fused LN1+shift+QKV+attn(reg-PV)+proj+residual-in-regs. K2: M=256 MLP, weights
// triple-buffered via global_load_lds + counted vmcnt, ONE barrier/chunk, plain stores.
#include <hip/hip_runtime.h>
#include <math.h>

typedef __attribute__((ext_vector_type(8))) short bf16x8;
typedef __attribute__((ext_vector_type(4))) short bf16x4;
typedef __attribute__((ext_vector_type(4))) float f32x4;
typedef __attribute__((ext_vector_type(4))) unsigned short u16x4;

#define DEVI __device__ __forceinline__

DEVI float b2f(unsigned int u){ union{unsigned int i; float f;} c; c.i = u<<16; return c.f; }
DEVI unsigned short f2b(float f){
  union{float f; unsigned int i;} c; c.f = f;
  unsigned int r = c.i + 0x7fffu + ((c.i>>16)&1u);
  return (unsigned short)(r>>16);
}
DEVI unsigned int pack2(float a, float b){
  return (unsigned int)f2b(a) | ((unsigned int)f2b(b)<<16);
}
DEVI void unpack8(uint4 u, float* f){
  f[0]=b2f(u.x&0xffffu); f[1]=b2f(u.x>>16);
  f[2]=b2f(u.y&0xffffu); f[3]=b2f(u.y>>16);
  f[4]=b2f(u.z&0xffffu); f[5]=b2f(u.z>>16);
  f[6]=b2f(u.w&0xffffu); f[7]=b2f(u.w>>16);
}
DEVI f32x4 mfma16(bf16x8 a, bf16x8 b, f32x4 c){
  return __builtin_amdgcn_mfma_f32_16x16x32_bf16(a, b, c, 0, 0, 0);
}
DEVI f32x4 mfma16x16(bf16x4 a, bf16x4 b, f32x4 c){
#if __has_builtin(__builtin_amdgcn_mfma_f32_16x16x16bf16_1k)
  return __builtin_amdgcn_mfma_f32_16x16x16bf16_1k(a, b, c, 0, 0, 0);
#else
  f32x4 d = c;
  asm volatile("v_mfma_f32_16x16x16_bf16 %0, %1, %2, %0" : "+v"(d) : "v"(a), "v"(b));
  return d;
#endif
}
// gelu tanh-form as u * sigmoid(2y)
DEVI float gelu_fast(float u){
  const float y2 = 1.5957691216057308f*(u + 0.044715f*u*u*u);
  return u / (1.f + __expf(-y2));
}
// XOR swizzles
DEVI int swzA(int row, int byi){ return row*256 + (byi ^ ((row&7)<<4)); }      // rows x 128 bf16
DEVI int swzQ(int row, int byi){ return row*64  + (byi ^ (((row>>1)&3)<<4)); } // 64x32  bf16
DEVI int swzO(int row, int byc){ return row*512 + (byc ^ ((row&7)<<4) ^ (((byc>>7)&3)<<5)); } // 64x128 f32

// ---------------- K0: weights -> bf16 MFMA-fragment order + rpb expansion ----------------
__global__ void k_prep(const float* __restrict__ qkvw, const float* __restrict__ projw,
                       const float* __restrict__ w1,   const float* __restrict__ w2,
                       const float* __restrict__ rpbt,
                       ushort* __restrict__ qkvF, ushort* __restrict__ projF,
                       ushort* __restrict__ w1F,  ushort* __restrict__ w2F,
                       ushort* __restrict__ rpbE)
{
  const int t = blockIdx.x*256 + threadIdx.x;   // 0..16383
  const int l = t&63, fr = t>>6;                // frag id 0..255
  const int l15 = l&15, l4 = l>>4;
  { // rpbE[head][q][k] bf16
    const int head = t>>12, q = (t>>6)&63, k = t&63;
    const int di = (q>>3)-(k>>3)+7, dj = (q&7)-(k&7)+7;
    rpbE[t] = f2b(rpbt[(di*15+dj)*4 + head]);
  }
  { // w2F: 256 frags x 512B ; lane: w2[hid0+e][oc], e=0..3
    const int c = fr>>5, og = (fr>>2)&7, h = fr&3;
    const int oc = og*16 + l15, hid0 = c*64 + h*16 + l4*4;
    ushort* d = w2F + (size_t)fr*256 + l*4;
    #pragma unroll
    for(int e=0;e<4;e++) d[e] = f2b(w2[(size_t)(hid0+e)*128 + oc]);
  }
  if (fr < 128){ // w1F
    const int c = fr>>4, hg = (fr>>2)&3, kk = fr&3;
    const int hid = c*64 + hg*16 + l15, k0 = kk*32 + l4*8;
    ushort* d = w1F + (size_t)fr*512 + l*8;
    #pragma unroll
    for(int e=0;e<8;e++) d[e] = f2b(w1[(size_t)(k0+e)*512 + hid]);
  }
  if (fr < 96){ // qkvF: fr = (s3*8+g)*4+kk
    const int s3 = fr>>5, g = (fr>>2)&7, kk = fr&3;
    const int col = s3*128 + g*16 + l15, k0 = kk*32 + l4*8;
    ushort* d = qkvF + (size_t)fr*512 + l*8;
    #pragma unroll
    for(int e=0;e<8;e++) d[e] = f2b(qkvw[(size_t)(k0+e)*384 + col]);
  }
  if (fr < 32){ // projF
    const int g = fr>>2, kk = fr&3;
    const int col = g*16 + l15, k0 = kk*32 + l4*8;
    ushort* d = projF + (size_t)fr*512 + l*8;
    #pragma unroll
    for(int e=0;e<8;e++) d[e] = f2b(projw[(size_t)(k0+e)*128 + col]);
  }
}

// ---------------- K1: fused window attention (R16-validated) ----------------
__global__ __launch_bounds__(256,3) void k_attn(
    const float*  __restrict__ x,
    const float*  __restrict__ g1, const float* __restrict__ be1,
    const ushort* __restrict__ qkvF, const float* __restrict__ qkvb,
    const ushort* __restrict__ projF, const float* __restrict__ projb,
    const ushort* __restrict__ rpbE,
    ushort* __restrict__ x2w)
{
  __shared__ __align__(16) char smem[49152];
  const int tid  = threadIdx.x;
  const int wave = tid>>6, lane = tid&63;
  const int l15 = lane&15, l4 = lane>>4;
  const int wid = blockIdx.x;
  const int b   = wid>>6, wim = wid&63;
  const int wh  = wim>>3, wv = wim&7;

  char* const smA  = smem;                      // 16 KB: LN1 tile / attn-O
  char* const smQ  = smem + 16384 + wave*8192;  // 4 KB per head
  char* const smK  = smQ + 4096;                // 4 KB per head
  char* const smR  = smem + 16384;              // 32 KB fp32 proj restage

  const f32x4 Z = {0.f,0.f,0.f,0.f};
  const int t_row = tid>>2;
  const int cg    = (tid&3)*32;
  const int ti_r = t_row>>3, tj_r = t_row&7;
  const int ho_r = (wh*8+ti_r+4)&63, wo_r = (wv*8+tj_r+4)&63;
  const size_t growbase = ((size_t)(b*4096 + ho_r*64 + wo_r))*128;

  float xraw[32];   // shifted-gathered x row-chunk: kept live for the residual

  { // ---- Phase 1: gather (roll -4,-4) + LN1 -> smA ----
    const float* src = x + growbase + cg;
    #pragma unroll
    for(int q=0;q<8;q++){
      const float4 f4 = *(const float4*)(src + q*4);
      xraw[q*4+0]=f4.x; xraw[q*4+1]=f4.y; xraw[q*4+2]=f4.z; xraw[q*4+3]=f4.w;
    }
    float s=0.f, ss=0.f;
    #pragma unroll
    for(int e=0;e<32;e++){ s+=xraw[e]; ss+=xraw[e]*xraw[e]; }
    s += __shfl_xor(s,1); ss += __shfl_xor(ss,1);
    s += __shfl_xor(s,2); ss += __shfl_xor(ss,2);
    const float mean = s*(1.f/128.f);
    const float varv = fmaxf(ss*(1.f/128.f) - mean*mean, 0.f);
    const float rstd = rsqrtf(varv + 1e-5f);
    #pragma unroll
    for(int q=0;q<4;q++){
      const float4 ga = *(const float4*)(g1 +cg+q*8);
      const float4 gb = *(const float4*)(g1 +cg+q*8+4);
      const float4 ba = *(const float4*)(be1+cg+q*8);
      const float4 bb = *(const float4*)(be1+cg+q*8+4);
      const float* vp = xraw + q*8;
      uint4 pk;
      pk.x = pack2((vp[0]-mean)*rstd*ga.x+ba.x, (vp[1]-mean)*rstd*ga.y+ba.y);
      pk.y = pack2((vp[2]-mean)*rstd*ga.z+ba.z, (vp[3]-mean)*rstd*ga.w+ba.w);
      pk.z = pack2((vp[4]-mean)*rstd*gb.x+bb.x, (vp[5]-mean)*rstd*gb.y+bb.y);
      pk.w = pack2((vp[6]-mean)*rstd*gb.z+bb.z, (vp[7]-mean)*rstd*gb.w+bb.w);
      *(uint4*)(smA + swzA(t_row, cg*2 + q*16)) = pk;
    }
  }
  __syncthreads();

  const int headc = wave*32;
  bf16x4 Vf[4][2];   // V in registers (PV B-frags)

  { // ---- Phase 2: QKV ----
    #pragma unroll
    for(int s3=0;s3<3;s3++){
      f32x4 acc[4][2];
      #pragma unroll
      for(int rt=0;rt<4;rt++){ acc[rt][0]=Z; acc[rt][1]=Z; }
      bf16x8 bfr[2][4];
      #pragma unroll
      for(int ct=0;ct<2;ct++)
        #pragma unroll
        for(int kk=0;kk<4;kk++)
          bfr[ct][kk] = *(const bf16x8*)(qkvF + (size_t)((s3*8 + wave*2 + ct)*4 + kk)*512 + lane*8);
      #pragma unroll
      for(int kk=0;kk<4;kk++){
        bf16x8 afr[4];
        #pragma unroll
        for(int rt=0;rt<4;rt++)
          afr[rt] = *(const bf16x8*)(smA + swzA(rt*16+l15, kk*64 + l4*16));
        #pragma unroll
        for(int rt=0;rt<4;rt++)
          #pragma unroll
          for(int ct=0;ct<2;ct++)
            acc[rt][ct] = mfma16(afr[rt], bfr[ct][kk], acc[rt][ct]);
      }
      #pragma unroll
      for(int ct=0;ct<2;ct++){
        const int hd = ct*16 + l15;
        const float bias = qkvb[s3*128 + headc + hd];
        if (s3==2){
          #pragma unroll
          for(int rt=0;rt<4;rt++){
            union { uint2 u; bf16x4 v; } cv;
            cv.u.x = pack2(acc[rt][ct][0]+bias, acc[rt][ct][1]+bias);
            cv.u.y = pack2(acc[rt][ct][2]+bias, acc[rt][ct][3]+bias);
            Vf[rt][ct] = cv.v;
          }
        } else {
          char* const dst = (s3==0) ? smQ : smK;
          const float sc = (s3==0) ? 0.17677669529663687f : 1.f;
          #pragma unroll
          for(int rt=0;rt<4;rt++){
            const int t0 = rt*16 + l4*4;
            #pragma unroll
            for(int j=0;j<4;j++)
              *(ushort*)(dst + swzQ(t0+j, hd*2)) = f2b((acc[rt][ct][j]+bias)*sc);
          }
        }
      }
    }
  }
  __syncthreads();

  // ---- Phase 3+4: S^T scores + rpb + mask + softmax + PV ----
  f32x4 O[4][2];
  #pragma unroll
  for(int rt=0;rt<4;rt++){ O[rt][0]=Z; O[rt][1]=Z; }
  {
    bf16x8 kfr[4];
    #pragma unroll
    for(int g=0; g<4; ++g)
      kfr[g] = *(const bf16x8*)(smK + swzQ(g*16+l15, l4*16));
    const bool edge = (wh==7) || (wv==7);
    #pragma unroll
    for(int rt=0; rt<4; ++rt){
      const bf16x8 qf = *(const bf16x8*)(smQ + swzQ(rt*16+l15, l4*16));
      f32x4 S[4];
      #pragma unroll
      for(int g=0; g<4; ++g)
        S[g] = mfma16(kfr[g], qf, Z);     // S^T
      const int q = rt*16 + l15;
      int regq = 0;
      if (edge){
        const int qi=q>>3, qj=q&7;
        regq = ((wh<7)?0:((qi<4)?1:2))*3 + ((wv<7)?0:((qj<4)?1:2));
      }
      const ushort* rbase = rpbE + wave*4096 + q*64 + l4*4;
      #pragma unroll
      for(int g=0; g<4; ++g){
        const u16x4 rb = *(const u16x4*)(rbase + g*16);
        #pragma unroll
        for(int j=0;j<4;j++){
          float add = b2f(rb[j]);
          if (edge){
            const int k = g*16 + l4*4 + j;
            const int ki=k>>3, kj=k&7;
            const int regk = ((wh<7)?0:((ki<4)?1:2))*3 + ((wv<7)?0:((kj<4)?1:2));
            if (regk != regq) add -= 100.f;
          }
          S[g][j] += add;
        }
      }
      float mx = -1e30f;
      #pragma unroll
      for(int g=0;g<4;g++)
        #pragma unroll
        for(int j=0;j<4;j++) mx = fmaxf(mx, S[g][j]);
      mx = fmaxf(mx, __shfl_xor(mx,16));
      mx = fmaxf(mx, __shfl_xor(mx,32));
      float sm = 0.f;
      #pragma unroll
      for(int g=0;g<4;g++)
        #pragma unroll
        for(int j=0;j<4;j++){ const float e = __expf(S[g][j]-mx); S[g][j]=e; sm+=e; }
      sm += __shfl_xor(sm,16);
      sm += __shfl_xor(sm,32);
      const float inv = 1.f/sm;
      #pragma unroll
      for(int g=0;g<4;g++){
        union { uint2 u; bf16x4 v; } cv;
        cv.u.x = pack2(S[g][0]*inv, S[g][1]*inv);
        cv.u.y = pack2(S[g][2]*inv, S[g][3]*inv);
        #pragma unroll
        for(int cvi=0;cvi<2;cvi++)
          O[rt][cvi] = mfma16x16(cv.v, Vf[g][cvi], O[rt][cvi]);
      }
    }
    #pragma unroll
    for(int rt=0;rt<4;rt++)
      #pragma unroll
      for(int cvi=0;cvi<2;cvi++)
        #pragma unroll
        for(int j=0;j<4;j++)
          *(ushort*)(smA + swzA(rt*16+l4*4+j, (headc + cvi*16 + l15)*2)) = f2b(O[rt][cvi][j]);
  }
  __syncthreads();

  { // ---- Phase 5: proj + bias -> smR (fp32, swzO) ----
    f32x4 PR[4][2];
    #pragma unroll
    for(int rt=0;rt<4;rt++){ PR[rt][0]=Z; PR[rt][1]=Z; }
    bf16x8 pb[2][4];
    #pragma unroll
    for(int ct=0;ct<2;ct++)
      #pragma unroll
      for(int kk=0;kk<4;kk++)
        pb[ct][kk] = *(const bf16x8*)(projF + (size_t)((wave*2+ct)*4 + kk)*512 + lane*8);
    #pragma unroll
    for(int kk=0;kk<4;kk++){
      bf16x8 afr[4];
      #pragma unroll
      for(int rt=0;rt<4;rt++)
        afr[rt] = *(const bf16x8*)(smA + swzA(rt*16+l15, kk*64 + l4*16));
      #pragma unroll
      for(int rt=0;rt<4;rt++)
        #pragma unroll
        for(int ct=0;ct<2;ct++)
          PR[rt][ct] = mfma16(afr[rt], pb[ct][kk], PR[rt][ct]);
    }
    #pragma unroll
    for(int ct=0;ct<2;ct++){
      const int col = headc + ct*16 + l15;
      const float bias = projb[col];
      #pragma unroll
      for(int rt=0;rt<4;rt++)
        #pragma unroll
        for(int j=0;j<4;j++)
          *(float*)(smR + swzO(rt*16+l4*4+j, col*4)) = PR[rt][ct][j] + bias;
    }
  }
  __syncthreads();

  { // ---- Phase 6: x2 = x(regs) + projout; uint4 stores ----
    ushort* drow = x2w + ((size_t)(wid*64 + t_row))*128 + cg;
    #pragma unroll
    for(int q=0;q<4;q++){
      const f32x4 oa = *(const f32x4*)(smR + swzO(t_row, (cg+q*8  )*4));
      const f32x4 ob = *(const f32x4*)(smR + swzO(t_row, (cg+q*8+4)*4));
      const float* vp = xraw + q*8;
      uint4 pk;
      pk.x = pack2(oa[0]+vp[0], oa[1]+vp[1]);
      pk.y = pack2(oa[2]+vp[2], oa[3]+vp[3]);
      pk.z = pack2(ob[0]+vp[4], ob[1]+vp[5]);
      pk.w = pack2(ob[2]+vp[6], ob[3]+vp[7]);
      *(uint4*)(drow + q*8) = pk;
    }
  }
}

// ---------------- K2: MLP, triple-buffered weights, ONE barrier per chunk ----------------
__global__ __launch_bounds__(1024) void k_mlp2(
    const ushort* __restrict__ x2w,
    const float* __restrict__ g2, const float* __restrict__ be2,
    const ushort* __restrict__ w1F, const float* __restrict__ bb1,
    const ushort* __restrict__ w2F, const float* __restrict__ bb2,
    float* __restrict__ outp)
{
  extern __shared__ __align__(16) char smem[];  // 100352 B: buf0/1/2 at 0/32K/64K (+smB1 at 96K)
  float* const smB1 = (float*)(smem + 98304);
  const int tid  = threadIdx.x;
  const int wave = tid>>6, lane = tid&63;      // wave 0..15
  const int l15 = lane&15, l4 = lane>>4;
  const int gblk = blockIdx.x;                 // 0..511 (4 windows each)
  const f32x4 Z = {0.f,0.f,0.f,0.f};

  if (tid < 512) smB1[tid] = bb1[tid];

  // ---- LN2: single pass, 256 tokens -> smem[0,64K) (swzA) ----
  {
    const int tk = tid>>2;
    const int cg = (tid&3)*32;
    const ushort* src = x2w + ((size_t)(gblk*256 + tk))*128 + cg;
    float v[32];
    unpack8(*(const uint4*)(src   ), v   );
    unpack8(*(const uint4*)(src+ 8), v+ 8);
    unpack8(*(const uint4*)(src+16), v+16);
    unpack8(*(const uint4*)(src+24), v+24);
    float s=0.f, ss=0.f;
    #pragma unroll
    for(int e=0;e<32;e++){ s+=v[e]; ss+=v[e]*v[e]; }
    s += __shfl_xor(s,1); ss += __shfl_xor(ss,1);
    s += __shfl_xor(s,2); ss += __shfl_xor(ss,2);
    const float mean = s*(1.f/128.f);
    const float varv = fmaxf(ss*(1.f/128.f) - mean*mean, 0.f);
    const float rstd = rsqrtf(varv + 1e-5f);
    #pragma unroll
    for(int q=0;q<4;q++){
      const float4 ga = *(const float4*)(g2 +cg+q*8);
      const float4 gb = *(const float4*)(g2 +cg+q*8+4);
      const float4 ba = *(const float4*)(be2+cg+q*8);
      const float4 bb = *(const float4*)(be2+cg+q*8+4);
      const float* vp = v + q*8;
      uint4 pk;
      pk.x = pack2((vp[0]-mean)*rstd*ga.x+ba.x, (vp[1]-mean)*rstd*ga.y+ba.y);
      pk.y = pack2((vp[2]-mean)*rstd*ga.z+ba.z, (vp[3]-mean)*rstd*ga.w+ba.w);
      pk.z = pack2((vp[4]-mean)*rstd*gb.x+bb.x, (vp[5]-mean)*rstd*gb.y+bb.y);
      pk.w = pack2((vp[6]-mean)*rstd*gb.z+bb.z, (vp[7]-mean)*rstd*gb.w+bb.w);
      *(uint4*)(smem + swzA(tk, cg*2 + q*16)) = pk;
    }
  }
  __syncthreads();

  // ---- extract X fragments to registers (smX dies after this) ----
  const int trow = wave*16 + l15;   // this wave's 16 tokens
  bf16x8 xf[4];
  #pragma unroll
  for(int kk=0;kk<4;++kk)
    xf[kk] = *(const bf16x8*)(smem + swzA(trow, kk*64 + l4*16));
  __syncthreads();   // all waves done reading smX -> weight buffers may overwrite

  // ---- async weight staging: waves 0-7 stage w1 (16KB), waves 8-15 stage w2 (16KB) ----
  const ushort* const wsrc = (wave<8) ? w1F : w2F;
  const int ldsoff = ((wave<8)?0:16384) + (wave&7)*2048;   // byte offset within buf
  const int subsh  = (wave&7)*1024;                        // ushort offset within 8192-ushort chunk
  #define STAGE_CHUNK(cc, bufbase) do{ \
    const ushort* gsrc = wsrc + (size_t)(cc)*8192 + subsh + lane*8; \
    char* lb = (bufbase) + ldsoff; \
    __builtin_amdgcn_global_load_lds((const unsigned int*)(gsrc     ), (unsigned int*)(lb      ), 16, 0, 0); \
    __builtin_amdgcn_global_load_lds((const unsigned int*)(gsrc+512 ), (unsigned int*)(lb+1024 ), 16, 0, 0); \
  }while(0)

  STAGE_CHUNK(0, smem);
  STAGE_CHUNK(1, smem + 32768);
  // outstanding per wave: chunk0 (2 loads) + chunk1 (2 loads)

  f32x4 OA[8];
  #pragma unroll
  for(int ocg=0;ocg<8;++ocg) OA[ocg]=Z;

  for (int c=0; c<8; ++c){
    // counted wait: my chunk-c loads (oldest 2) done; chunk-(c+1)'s 2 may stay in flight
    if (c < 7) asm volatile("s_waitcnt vmcnt(2)" ::: "memory");
    else       asm volatile("s_waitcnt vmcnt(0)" ::: "memory");
    __builtin_amdgcn_s_barrier();          // chunk c landed everywhere; all waves finished iter c-1
    __builtin_amdgcn_sched_barrier(0);
    // stage c+2 into buf[(c+2)%3] = buffer last read in iter c-1 (all waves past it)
    if (c < 6) STAGE_CHUNK(c+2, smem + 32768*((c+2)%3));

    char* const buf = smem + 32768*(c%3);
    const int hidb = c*64;
    f32x4 acc1[4] = {Z,Z,Z,Z};
    #pragma unroll
    for(int hg=0; hg<4; ++hg)
      #pragma unroll
      for(int kk=0; kk<4; ++kk){
        const bf16x8 wf = *(const bf16x8*)(buf + (hg*4+kk)*1024 + lane*16);
        acc1[hg] = mfma16(wf, xf[kk], acc1[hg]);
      }
    bf16x4 Hf[4];
    #pragma unroll
    for(int hg=0; hg<4; ++hg){
      const float4 b4 = *(const float4*)(&smB1[hidb + hg*16 + l4*4]);
      bf16x4 hv;
      hv[0] = (short)f2b(gelu_fast(acc1[hg][0]+b4.x));
      hv[1] = (short)f2b(gelu_fast(acc1[hg][1]+b4.y));
      hv[2] = (short)f2b(gelu_fast(acc1[hg][2]+b4.z));
      hv[3] = (short)f2b(gelu_fast(acc1[hg][3]+b4.w));
      Hf[hg] = hv;
    }
    #pragma unroll
    for(int ocg=0; ocg<8; ++ocg)
      #pragma unroll
      for(int hg=0; hg<4; ++hg){
        const bf16x4 w2f = *(const bf16x4*)(buf + 16384 + (ocg*4+hg)*512 + lane*8);
        OA[ocg] = mfma16x16(w2f, Hf[hg], OA[ocg]);
      }
    __builtin_amdgcn_sched_barrier(0);
  }
  #undef STAGE_CHUNK

  // ---- epilogue: restage raw x2 into smem[0,64K) (aliases bufs; safe after barrier) ----
  __syncthreads();
  {
    const int tk = tid>>2;
    const int cg = (tid&3)*32;
    const uint4* src = (const uint4*)(x2w + ((size_t)(gblk*256 + tk))*128 + cg);
    #pragma unroll
    for(int q=0;q<4;q++) *(uint4*)(smem + swzA(tk, cg*2 + q*16)) = src[q];
  }
  __syncthreads();
  {
    const int tk  = trow;
    const int wid = gblk*4 + (tk>>6);
    const int n   = tk & 63;
    const int bb  = wid>>6, wim = wid&63;
    const int wh  = wim>>3, wv = wim&7;
    const int ti  = n>>3,  tj = n&7;
    const int ho  = (wh*8+ti+4)&63, wo = (wv*8+tj+4)&63;
    float* const drow = outp + ((size_t)(bb*4096 + ho*64 + wo))*128;
    #pragma unroll
    for(int ocg=0; ocg<8; ++ocg){
      const int oc = ocg*16 + l4*4;
      const float4 b4 = *(const float4*)(bb2 + oc);
      const u16x4 xr = *(const u16x4*)(smem + swzA(tk, oc*2));
      f32x4 r = OA[ocg];
      r[0] += b4.x + b2f(xr[0]);
      r[1] += b4.y + b2f(xr[1]);
      r[2] += b4.z + b2f(xr[2]);
      r[3] += b4.w + b2f(xr[3]);
      *(f32x4*)(drow + oc) = r;   // plain store: L2 write-combines full lines
    }
  }
}

extern "C" void kernel_launch(void* const* d_in, const int* in_sizes, int n_in,
                              void* d_out, int out_size, void* d_ws, size_t ws_size,
                              hipStream_t stream) {
  (void)in_sizes; (void)n_in; (void)out_size; (void)ws_size;
  const float* x     = (const float*)d_in[0];
  const float* n1g   = (const float*)d_in[1];
  const float* n1b   = (const float*)d_in[2];
  const float* qkvw  = (const float*)d_in[3];
  const float* qkvb  = (const float*)d_in[4];
  const float* projw = (const float*)d_in[5];
  const float* projb = (const float*)d_in[6];
  const float* rpbt  = (const float*)d_in[7];
  const float* n2g   = (const float*)d_in[8];
  const float* n2b   = (const float*)d_in[9];
  const float* w1    = (const float*)d_in[10];
  const float* b1    = (const float*)d_in[11];
  const float* w2    = (const float*)d_in[12];
  const float* b2    = (const float*)d_in[13];
  float* outp = (float*)d_out;

  ushort* ws    = (ushort*)d_ws;
  ushort* x2w   = ws;                  // 16,777,216 bf16
  ushort* qkvF  = ws + 16777216;       // 49152
  ushort* projF = qkvF + 49152;        // 16384
  ushort* w1F   = projF + 16384;       // 65536 (8 chunks x 8192)
  ushort* w2F   = w1F + 65536;         // 65536 (8 chunks x 8192)
  ushort* rpbE  = w2F + 65536;         // 16384

  k_prep<<<64, 256, 0, stream>>>(qkvw, projw, w1, w2, rpbt, qkvF, projF, w1F, w2F, rpbE);
  k_attn<<<2048, 256, 0, stream>>>(x, n1g, n1b, qkvF, qkvb, projF, projb, rpbE, x2w);
  k_mlp2<<<512, 1024, 100352, stream>>>(x2w, n2g, n2b, w1F, b1, w2F, b2, outp);
}

// Round 20
// 171.672 us; speedup vs baseline: 1.0973x; 1.0105x over previous
//
// Swin block fwd, MI355X gfx950. Round 20: R19 + ONE change — k_mlp2 keeps the raw x2 row
// (4x uint4 packed bf16, 16 VGPR) in registers from LN2; epilogue writes it to LDS from regs
// instead of re-reading 32MB of x2w from global. Same mechanism as R16's validated xraw win.
#include <hip/hip_runtime.h>
#include <math.h>

typedef __attribute__((ext_vector_type(8))) short bf16x8;
typedef __attribute__((ext_vector_type(4))) short bf16x4;
typedef __attribute__((ext_vector_type(4))) float f32x4;
typedef __attribute__((ext_vector_type(4))) unsigned short u16x4;

#define DEVI __device__ __forceinline__

DEVI float b2f(unsigned int u){ union{unsigned int i; float f;} c; c.i = u<<16; return c.f; }
DEVI unsigned short f2b(float f){
  union{float f; unsigned int i;} c; c.f = f;
  unsigned int r = c.i + 0x7fffu + ((c.i>>16)&1u);
  return (unsigned short)(r>>16);
}
DEVI unsigned int pack2(float a, float b){
  return (unsigned int)f2b(a) | ((unsigned int)f2b(b)<<16);
}
DEVI void unpack8(uint4 u, float* f){
  f[0]=b2f(u.x&0xffffu); f[1]=b2f(u.x>>16);
  f[2]=b2f(u.y&0xffffu); f[3]=b2f(u.y>>16);
  f[4]=b2f(u.z&0xffffu); f[5]=b2f(u.z>>16);
  f[6]=b2f(u.w&0xffffu); f[7]=b2f(u.w>>16);
}
DEVI f32x4 mfma16(bf16x8 a, bf16x8 b, f32x4 c){
  return __builtin_amdgcn_mfma_f32_16x16x32_bf16(a, b, c, 0, 0, 0);
}
DEVI f32x4 mfma16x16(bf16x4 a, bf16x4 b, f32x4 c){
#if __has_builtin(__builtin_amdgcn_mfma_f32_16x16x16bf16_1k)
  return __builtin_amdgcn_mfma_f32_16x16x16bf16_1k(a, b, c, 0, 0, 0);
#else
  f32x4 d = c;
  asm volatile("v_mfma_f32_16x16x16_bf16 %0, %1, %2, %0" : "+v"(d) : "v"(a), "v"(b));
  return d;
#endif
}
// gelu tanh-form as u * sigmoid(2y)
DEVI float gelu_fast(float u){
  const float y2 = 1.5957691216057308f*(u + 0.044715f*u*u*u);
  return u / (1.f + __expf(-y2));
}
// XOR swizzles
DEVI int swzA(int row, int byi){ return row*256 + (byi ^ ((row&7)<<4)); }      // rows x 128 bf16
DEVI int swzQ(int row, int byi){ return row*64  + (byi ^ (((row>>1)&3)<<4)); } // 64x32  bf16
DEVI int swzO(int row, int byc){ return row*512 + (byc ^ ((row&7)<<4) ^ (((byc>>7)&3)<<5)); } // 64x128 f32

// ---------------- K0: weights -> bf16 MFMA-fragment order + rpb expansion ----------------
__global__ void k_prep(const float* __restrict__ qkvw, const float* __restrict__ projw,
                       const float* __restrict__ w1,   const float* __restrict__ w2,
                       const float* __restrict__ rpbt,
                       ushort* __restrict__ qkvF, ushort* __restrict__ projF,
                       ushort* __restrict__ w1F,  ushort* __restrict__ w2F,
                       ushort* __restrict__ rpbE)
{
  const int t = blockIdx.x*256 + threadIdx.x;   // 0..16383
  const int l = t&63, fr = t>>6;                // frag id 0..255
  const int l15 = l&15, l4 = l>>4;
  { // rpbE[head][q][k] bf16
    const int head = t>>12, q = (t>>6)&63, k = t&63;
    const int di = (q>>3)-(k>>3)+7, dj = (q&7)-(k&7)+7;
    rpbE[t] = f2b(rpbt[(di*15+dj)*4 + head]);
  }
  { // w2F: 256 frags x 512B ; lane: w2[hid0+e][oc], e=0..3
    const int c = fr>>5, og = (fr>>2)&7, h = fr&3;
    const int oc = og*16 + l15, hid0 = c*64 + h*16 + l4*4;
    ushort* d = w2F + (size_t)fr*256 + l*4;
    #pragma unroll
    for(int e=0;e<4;e++) d[e] = f2b(w2[(size_t)(hid0+e)*128 + oc]);
  }
  if (fr < 128){ // w1F
    const int c = fr>>4, hg = (fr>>2)&3, kk = fr&3;
    const int hid = c*64 + hg*16 + l15, k0 = kk*32 + l4*8;
    ushort* d = w1F + (size_t)fr*512 + l*8;
    #pragma unroll
    for(int e=0;e<8;e++) d[e] = f2b(w1[(size_t)(k0+e)*512 + hid]);
  }
  if (fr < 96){ // qkvF: fr = (s3*8+g)*4+kk
    const int s3 = fr>>5, g = (fr>>2)&7, kk = fr&3;
    const int col = s3*128 + g*16 + l15, k0 = kk*32 + l4*8;
    ushort* d = qkvF + (size_t)fr*512 + l*8;
    #pragma unroll
    for(int e=0;e<8;e++) d[e] = f2b(qkvw[(size_t)(k0+e)*384 + col]);
  }
  if (fr < 32){ // projF
    const int g = fr>>2, kk = fr&3;
    const int col = g*16 + l15, k0 = kk*32 + l4*8;
    ushort* d = projF + (size_t)fr*512 + l*8;
    #pragma unroll
    for(int e=0;e<8;e++) d[e] = f2b(projw[(size_t)(k0+e)*128 + col]);
  }
}

// ---------------- K1: fused window attention (R16-validated) ----------------
__global__ __launch_bounds__(256,3) void k_attn(
    const float*  __restrict__ x,
    const float*  __restrict__ g1, const float* __restrict__ be1,
    const ushort* __restrict__ qkvF, const float* __restrict__ qkvb,
    const ushort* __restrict__ projF, const float* __restrict__ projb,
    const ushort* __restrict__ rpbE,
    ushort* __restrict__ x2w)
{
  __shared__ __align__(16) char smem[49152];
  const int tid  = threadIdx.x;
  const int wave = tid>>6, lane = tid&63;
  const int l15 = lane&15, l4 = lane>>4;
  const int wid = blockIdx.x;
  const int b   = wid>>6, wim = wid&63;
  const int wh  = wim>>3, wv = wim&7;

  char* const smA  = smem;                      // 16 KB: LN1 tile / attn-O
  char* const smQ  = smem + 16384 + wave*8192;  // 4 KB per head
  char* const smK  = smQ + 4096;                // 4 KB per head
  char* const smR  = smem + 16384;              // 32 KB fp32 proj restage

  const f32x4 Z = {0.f,0.f,0.f,0.f};
  const int t_row = tid>>2;
  const int cg    = (tid&3)*32;
  const int ti_r = t_row>>3, tj_r = t_row&7;
  const int ho_r = (wh*8+ti_r+4)&63, wo_r = (wv*8+tj_r+4)&63;
  const size_t growbase = ((size_t)(b*4096 + ho_r*64 + wo_r))*128;

  float xraw[32];   // shifted-gathered x row-chunk: kept live for the residual

  { // ---- Phase 1: gather (roll -4,-4) + LN1 -> smA ----
    const float* src = x + growbase + cg;
    #pragma unroll
    for(int q=0;q<8;q++){
      const float4 f4 = *(const float4*)(src + q*4);
      xraw[q*4+0]=f4.x; xraw[q*4+1]=f4.y; xraw[q*4+2]=f4.z; xraw[q*4+3]=f4.w;
    }
    float s=0.f, ss=0.f;
    #pragma unroll
    for(int e=0;e<32;e++){ s+=xraw[e]; ss+=xraw[e]*xraw[e]; }
    s += __shfl_xor(s,1); ss += __shfl_xor(ss,1);
    s += __shfl_xor(s,2); ss += __shfl_xor(ss,2);
    const float mean = s*(1.f/128.f);
    const float varv = fmaxf(ss*(1.f/128.f) - mean*mean, 0.f);
    const float rstd = rsqrtf(varv + 1e-5f);
    #pragma unroll
    for(int q=0;q<4;q++){
      const float4 ga = *(const float4*)(g1 +cg+q*8);
      const float4 gb = *(const float4*)(g1 +cg+q*8+4);
      const float4 ba = *(const float4*)(be1+cg+q*8);
      const float4 bb = *(const float4*)(be1+cg+q*8+4);
      const float* vp = xraw + q*8;
      uint4 pk;
      pk.x = pack2((vp[0]-mean)*rstd*ga.x+ba.x, (vp[1]-mean)*rstd*ga.y+ba.y);
      pk.y = pack2((vp[2]-mean)*rstd*ga.z+ba.z, (vp[3]-mean)*rstd*ga.w+ba.w);
      pk.z = pack2((vp[4]-mean)*rstd*gb.x+bb.x, (vp[5]-mean)*rstd*gb.y+bb.y);
      pk.w = pack2((vp[6]-mean)*rstd*gb.z+bb.z, (vp[7]-mean)*rstd*gb.w+bb.w);
      *(uint4*)(smA + swzA(t_row, cg*2 + q*16)) = pk;
    }
  }
  __syncthreads();

  const int headc = wave*32;
  bf16x4 Vf[4][2];   // V in registers (PV B-frags)

  { // ---- Phase 2: QKV ----
    #pragma unroll
    for(int s3=0;s3<3;s3++){
      f32x4 acc[4][2];
      #pragma unroll
      for(int rt=0;rt<4;rt++){ acc[rt][0]=Z; acc[rt][1]=Z; }
      bf16x8 bfr[2][4];
      #pragma unroll
      for(int ct=0;ct<2;ct++)
        #pragma unroll
        for(int kk=0;kk<4;kk++)
          bfr[ct][kk] = *(const bf16x8*)(qkvF + (size_t)((s3*8 + wave*2 + ct)*4 + kk)*512 + lane*8);
      #pragma unroll
      for(int kk=0;kk<4;kk++){
        bf16x8 afr[4];
        #pragma unroll
        for(int rt=0;rt<4;rt++)
          afr[rt] = *(const bf16x8*)(smA + swzA(rt*16+l15, kk*64 + l4*16));
        #pragma unroll
        for(int rt=0;rt<4;rt++)
          #pragma unroll
          for(int ct=0;ct<2;ct++)
            acc[rt][ct] = mfma16(afr[rt], bfr[ct][kk], acc[rt][ct]);
      }
      #pragma unroll
      for(int ct=0;ct<2;ct++){
        const int hd = ct*16 + l15;
        const float bias = qkvb[s3*128 + headc + hd];
        if (s3==2){
          #pragma unroll
          for(int rt=0;rt<4;rt++){
            union { uint2 u; bf16x4 v; } cv;
            cv.u.x = pack2(acc[rt][ct][0]+bias, acc[rt][ct][1]+bias);
            cv.u.y = pack2(acc[rt][ct][2]+bias, acc[rt][ct][3]+bias);
            Vf[rt][ct] = cv.v;
          }
        } else {
          char* const dst = (s3==0) ? smQ : smK;
          const float sc = (s3==0) ? 0.17677669529663687f : 1.f;
          #pragma unroll
          for(int rt=0;rt<4;rt++){
            const int t0 = rt*16 + l4*4;
            #pragma unroll
            for(int j=0;j<4;j++)
              *(ushort*)(dst + swzQ(t0+j, hd*2)) = f2b((acc[rt][ct][j]+bias)*sc);
          }
        }
      }
    }
  }
  __syncthreads();

  // ---- Phase 3+4: S^T scores + rpb + mask + softmax + PV ----
  f32x4 O[4][2];
  #pragma unroll
  for(int rt=0;rt<4;rt++){ O[rt][0]=Z; O[rt][1]=Z; }
  {
    bf16x8 kfr[4];
    #pragma unroll
    for(int g=0; g<4; ++g)
      kfr[g] = *(const bf16x8*)(smK + swzQ(g*16+l15, l4*16));
    const bool edge = (wh==7) || (wv==7);
    #pragma unroll
    for(int rt=0; rt<4; ++rt){
      const bf16x8 qf = *(const bf16x8*)(smQ + swzQ(rt*16+l15, l4*16));
      f32x4 S[4];
      #pragma unroll
      for(int g=0; g<4; ++g)
        S[g] = mfma16(kfr[g], qf, Z);     // S^T
      const int q = rt*16 + l15;
      int regq = 0;
      if (edge){
        const int qi=q>>3, qj=q&7;
        regq = ((wh<7)?0:((qi<4)?1:2))*3 + ((wv<7)?0:((qj<4)?1:2));
      }
      const ushort* rbase = rpbE + wave*4096 + q*64 + l4*4;
      #pragma unroll
      for(int g=0; g<4; ++g){
        const u16x4 rb = *(const u16x4*)(rbase + g*16);
        #pragma unroll
        for(int j=0;j<4;j++){
          float add = b2f(rb[j]);
          if (edge){
            const int k = g*16 + l4*4 + j;
            const int ki=k>>3, kj=k&7;
            const int regk = ((wh<7)?0:((ki<4)?1:2))*3 + ((wv<7)?0:((kj<4)?1:2));
            if (regk != regq) add -= 100.f;
          }
          S[g][j] += add;
        }
      }
      float mx = -1e30f;
      #pragma unroll
      for(int g=0;g<4;g++)
        #pragma unroll
        for(int j=0;j<4;j++) mx = fmaxf(mx, S[g][j]);
      mx = fmaxf(mx, __shfl_xor(mx,16));
      mx = fmaxf(mx, __shfl_xor(mx,32));
      float sm = 0.f;
      #pragma unroll
      for(int g=0;g<4;g++)
        #pragma unroll
        for(int j=0;j<4;j++){ const float e = __expf(S[g][j]-mx); S[g][j]=e; sm+=e; }
      sm += __shfl_xor(sm,16);
      sm += __shfl_xor(sm,32);
      const float inv = 1.f/sm;
      #pragma unroll
      for(int g=0;g<4;g++){
        union { uint2 u; bf16x4 v; } cv;
        cv.u.x = pack2(S[g][0]*inv, S[g][1]*inv);
        cv.u.y = pack2(S[g][2]*inv, S[g][3]*inv);
        #pragma unroll
        for(int cvi=0;cvi<2;cvi++)
          O[rt][cvi] = mfma16x16(cv.v, Vf[g][cvi], O[rt][cvi]);
      }
    }
    #pragma unroll
    for(int rt=0;rt<4;rt++)
      #pragma unroll
      for(int cvi=0;cvi<2;cvi++)
        #pragma unroll
        for(int j=0;j<4;j++)
          *(ushort*)(smA + swzA(rt*16+l4*4+j, (headc + cvi*16 + l15)*2)) = f2b(O[rt][cvi][j]);
  }
  __syncthreads();

  { // ---- Phase 5: proj + bias -> smR (fp32, swzO) ----
    f32x4 PR[4][2];
    #pragma unroll
    for(int rt=0;rt<4;rt++){ PR[rt][0]=Z; PR[rt][1]=Z; }
    bf16x8 pb[2][4];
    #pragma unroll
    for(int ct=0;ct<2;ct++)
      #pragma unroll
      for(int kk=0;kk<4;kk++)
        pb[ct][kk] = *(const bf16x8*)(projF + (size_t)((wave*2+ct)*4 + kk)*512 + lane*8);
    #pragma unroll
    for(int kk=0;kk<4;kk++){
      bf16x8 afr[4];
      #pragma unroll
      for(int rt=0;rt<4;rt++)
        afr[rt] = *(const bf16x8*)(smA + swzA(rt*16+l15, kk*64 + l4*16));
      #pragma unroll
      for(int rt=0;rt<4;rt++)
        #pragma unroll
        for(int ct=0;ct<2;ct++)
          PR[rt][ct] = mfma16(afr[rt], pb[ct][kk], PR[rt][ct]);
    }
    #pragma unroll
    for(int ct=0;ct<2;ct++){
      const int col = headc + ct*16 + l15;
      const float bias = projb[col];
      #pragma unroll
      for(int rt=0;rt<4;rt++)
        #pragma unroll
        for(int j=0;j<4;j++)
          *(float*)(smR + swzO(rt*16+l4*4+j, col*4)) = PR[rt][ct][j] + bias;
    }
  }
  __syncthreads();

  { // ---- Phase 6: x2 = x(regs) + projout; uint4 stores ----
    ushort* drow = x2w + ((size_t)(wid*64 + t_row))*128 + cg;
    #pragma unroll
    for(int q=0;q<4;q++){
      const f32x4 oa = *(const f32x4*)(smR + swzO(t_row, (cg+q*8  )*4));
      const f32x4 ob = *(const f32x4*)(smR + swzO(t_row, (cg+q*8+4)*4));
      const float* vp = xraw + q*8;
      uint4 pk;
      pk.x = pack2(oa[0]+vp[0], oa[1]+vp[1]);
      pk.y = pack2(oa[2]+vp[2], oa[3]+vp[3]);
      pk.z = pack2(ob[0]+vp[4], ob[1]+vp[5]);
      pk.w = pack2(ob[2]+vp[6], ob[3]+vp[7]);
      *(uint4*)(drow + q*8) = pk;
    }
  }
}

// ---------------- K2: MLP, triple-buffered weights, ONE barrier per chunk ----------------
__global__ __launch_bounds__(1024) void k_mlp2(
    const ushort* __restrict__ x2w,
    const float* __restrict__ g2, const float* __restrict__ be2,
    const ushort* __restrict__ w1F, const float* __restrict__ bb1,
    const ushort* __restrict__ w2F, const float* __restrict__ bb2,
    float* __restrict__ outp)
{
  extern __shared__ __align__(16) char smem[];  // 100352 B: buf0/1/2 at 0/32K/64K (+smB1 at 96K)
  float* const smB1 = (float*)(smem + 98304);
  const int tid  = threadIdx.x;
  const int wave = tid>>6, lane = tid&63;      // wave 0..15
  const int l15 = lane&15, l4 = lane>>4;
  const int gblk = blockIdx.x;                 // 0..511 (4 windows each)
  const f32x4 Z = {0.f,0.f,0.f,0.f};

  if (tid < 512) smB1[tid] = bb1[tid];

  uint4 x2raw[4];   // raw packed-bf16 x2 row-chunk, kept live for the residual (16 VGPR)

  // ---- LN2: single pass, 256 tokens -> smem[0,64K) (swzA) ----
  {
    const int tk = tid>>2;
    const int cg = (tid&3)*32;
    const ushort* src = x2w + ((size_t)(gblk*256 + tk))*128 + cg;
    x2raw[0] = *(const uint4*)(src   );
    x2raw[1] = *(const uint4*)(src+ 8);
    x2raw[2] = *(const uint4*)(src+16);
    x2raw[3] = *(const uint4*)(src+24);
    float v[32];
    unpack8(x2raw[0], v   );
    unpack8(x2raw[1], v+ 8);
    unpack8(x2raw[2], v+16);
    unpack8(x2raw[3], v+24);
    float s=0.f, ss=0.f;
    #pragma unroll
    for(int e=0;e<32;e++){ s+=v[e]; ss+=v[e]*v[e]; }
    s += __shfl_xor(s,1); ss += __shfl_xor(ss,1);
    s += __shfl_xor(s,2); ss += __shfl_xor(ss,2);
    const float mean = s*(1.f/128.f);
    const float varv = fmaxf(ss*(1.f/128.f) - mean*mean, 0.f);
    const float rstd = rsqrtf(varv + 1e-5f);
    #pragma unroll
    for(int q=0;q<4;q++){
      const float4 ga = *(const float4*)(g2 +cg+q*8);
      const float4 gb = *(const float4*)(g2 +cg+q*8+4);
      const float4 ba = *(const float4*)(be2+cg+q*8);
      const float4 bb = *(const float4*)(be2+cg+q*8+4);
      const float* vp = v + q*8;
      uint4 pk;
      pk.x = pack2((vp[0]-mean)*rstd*ga.x+ba.x, (vp[1]-mean)*rstd*ga.y+ba.y);
      pk.y = pack2((vp[2]-mean)*rstd*ga.z+ba.z, (vp[3]-mean)*rstd*ga.w+ba.w);
      pk.z = pack2((vp[4]-mean)*rstd*gb.x+bb.x, (vp[5]-mean)*rstd*gb.y+bb.y);
      pk.w = pack2((vp[6]-mean)*rstd*gb.z+bb.z, (vp[7]-mean)*rstd*gb.w+bb.w);
      *(uint4*)(smem + swzA(tk, cg*2 + q*16)) = pk;
    }
  }
  __syncthreads();

  // ---- extract X fragments to registers (smX dies after this) ----
  const int trow = wave*16 + l15;   // this wave's 16 tokens
  bf16x8 xf[4];
  #pragma unroll
  for(int kk=0;kk<4;++kk)
    xf[kk] = *(const bf16x8*)(smem + swzA(trow, kk*64 + l4*16));
  __syncthreads();   // all waves done reading smX -> weight buffers may overwrite

  // ---- async weight staging: waves 0-7 stage w1 (16KB), waves 8-15 stage w2 (16KB) ----
  const ushort* const wsrc = (wave<8) ? w1F : w2F;
  const int ldsoff = ((wave<8)?0:16384) + (wave&7)*2048;   // byte offset within buf
  const int subsh  = (wave&7)*1024;                        // ushort offset within 8192-ushort chunk
  #define STAGE_CHUNK(cc, bufbase) do{ \
    const ushort* gsrc = wsrc + (size_t)(cc)*8192 + subsh + lane*8; \
    char* lb = (bufbase) + ldsoff; \
    __builtin_amdgcn_global_load_lds((const unsigned int*)(gsrc     ), (unsigned int*)(lb      ), 16, 0, 0); \
    __builtin_amdgcn_global_load_lds((const unsigned int*)(gsrc+512 ), (unsigned int*)(lb+1024 ), 16, 0, 0); \
  }while(0)

  STAGE_CHUNK(0, smem);
  STAGE_CHUNK(1, smem + 32768);
  // outstanding per wave: chunk0 (2 loads) + chunk1 (2 loads)

  f32x4 OA[8];
  #pragma unroll
  for(int ocg=0;ocg<8;++ocg) OA[ocg]=Z;

  for (int c=0; c<8; ++c){
    // counted wait: my chunk-c loads (oldest 2) done; chunk-(c+1)'s 2 may stay in flight
    if (c < 7) asm volatile("s_waitcnt vmcnt(2)" ::: "memory");
    else       asm volatile("s_waitcnt vmcnt(0)" ::: "memory");
    __builtin_amdgcn_s_barrier();          // chunk c landed everywhere; all waves finished iter c-1
    __builtin_amdgcn_sched_barrier(0);
    // stage c+2 into buf[(c+2)%3] = buffer last read in iter c-1 (all waves past it)
    if (c < 6) STAGE_CHUNK(c+2, smem + 32768*((c+2)%3));

    char* const buf = smem + 32768*(c%3);
    const int hidb = c*64;
    f32x4 acc1[4] = {Z,Z,Z,Z};
    #pragma unroll
    for(int hg=0; hg<4; ++hg)
      #pragma unroll
      for(int kk=0; kk<4; ++kk){
        const bf16x8 wf = *(const bf16x8*)(buf + (hg*4+kk)*1024 + lane*16);
        acc1[hg] = mfma16(wf, xf[kk], acc1[hg]);
      }
    bf16x4 Hf[4];
    #pragma unroll
    for(int hg=0; hg<4; ++hg){
      const float4 b4 = *(const float4*)(&smB1[hidb + hg*16 + l4*4]);
      bf16x4 hv;
      hv[0] = (short)f2b(gelu_fast(acc1[hg][0]+b4.x));
      hv[1] = (short)f2b(gelu_fast(acc1[hg][1]+b4.y));
      hv[2] = (short)f2b(gelu_fast(acc1[hg][2]+b4.z));
      hv[3] = (short)f2b(gelu_fast(acc1[hg][3]+b4.w));
      Hf[hg] = hv;
    }
    #pragma unroll
    for(int ocg=0; ocg<8; ++ocg)
      #pragma unroll
      for(int hg=0; hg<4; ++hg){
        const bf16x4 w2f = *(const bf16x4*)(buf + 16384 + (ocg*4+hg)*512 + lane*8);
        OA[ocg] = mfma16x16(w2f, Hf[hg], OA[ocg]);
      }
    __builtin_amdgcn_sched_barrier(0);
  }
  #undef STAGE_CHUNK

  // ---- epilogue: write raw x2 (regs) into smem[0,64K) — no global re-read ----
  __syncthreads();
  {
    const int tk = tid>>2;
    const int cg = (tid&3)*32;
    #pragma unroll
    for(int q=0;q<4;q++) *(uint4*)(smem + swzA(tk, cg*2 + q*16)) = x2raw[q];
  }
  __syncthreads();
  {
    const int tk  = trow;
    const int wid = gblk*4 + (tk>>6);
    const int n   = tk & 63;
    const int bb  = wid>>6, wim = wid&63;
    const int wh  = wim>>3, wv = wim&7;
    const int ti  = n>>3,  tj = n&7;
    const int ho  = (wh*8+ti+4)&63, wo = (wv*8+tj+4)&63;
    float* const drow = outp + ((size_t)(bb*4096 + ho*64 + wo))*128;
    #pragma unroll
    for(int ocg=0; ocg<8; ++ocg){
      const int oc = ocg*16 + l4*4;
      const float4 b4 = *(const float4*)(bb2 + oc);
      const u16x4 xr = *(const u16x4*)(smem + swzA(tk, oc*2));
      f32x4 r = OA[ocg];
      r[0] += b4.x + b2f(xr[0]);
      r[1] += b4.y + b2f(xr[1]);
      r[2] += b4.z + b2f(xr[2]);
      r[3] += b4.w + b2f(xr[3]);
      *(f32x4*)(drow + oc) = r;   // plain store: L2 write-combines full lines
    }
  }
}

extern "C" void kernel_launch(void* const* d_in, const int* in_sizes, int n_in,
                              void* d_out, int out_size, void* d_ws, size_t ws_size,
                              hipStream_t stream) {
  (void)in_sizes; (void)n_in; (void)out_size; (void)ws_size;
  const float* x     = (const float*)d_in[0];
  const float* n1g   = (const float*)d_in[1];
  const float* n1b   = (const float*)d_in[2];
  const float* qkvw  = (const float*)d_in[3];
  const float* qkvb  = (const float*)d_in[4];
  const float* projw = (const float*)d_in[5];
  const float* projb = (const float*)d_in[6];
  const float* rpbt  = (const float*)d_in[7];
  const float* n2g   = (const float*)d_in[8];
  const float* n2b   = (const float*)d_in[9];
  const float* w1    = (const float*)d_in[10];
  const float* b1    = (const float*)d_in[11];
  const float* w2    = (const float*)d_in[12];
  const float* b2    = (const float*)d_in[13];
  float* outp = (float*)d_out;

  ushort* ws    = (ushort*)d_ws;
  ushort* x2w   = ws;                  // 16,777,216 bf16
  ushort* qkvF  = ws + 16777216;       // 49152
  ushort* projF = qkvF + 49152;        // 16384
  ushort* w1F   = projF + 16384;       // 65536 (8 chunks x 8192)
  ushort* w2F   = w1F + 65536;         // 65536 (8 chunks x 8192)
  ushort* rpbE  = w2F + 65536;         // 16384

  k_prep<<<64, 256, 0, stream>>>(qkvw, projw, w1, w2, rpbt, qkvF, projF, w1F, w2F, rpbE);
  k_attn<<<2048, 256, 0, stream>>>(x, n1g, n1b, qkvF, qkvb, projF, projb, rpbE, x2w);
  k_mlp2<<<512, 1024, 100352, stream>>>(x2w, n2g, n2b, w1F, b1, w2F, b2, outp);
}